// Round 7
// baseline (620.899 us; speedup 1.0000x reference)
//
#include <hip/hip_runtime.h>
#include <hip/hip_cooperative_groups.h>
#include <cstddef>

namespace cg = cooperative_groups;

#define NNODE 4096
#define INF   512
#define OUTF  256
#define HID   8
#define CAP   128   // max degree; Binomial(4096,0.01) max ~67; padded to mult-of-16, <=80
#define GRID  512   // 2 blocks/CU co-resident: LDS 27.6KB*2<=160KB, VGPR<=256, 8 waves/CU

typedef __attribute__((ext_vector_type(8))) short short8;
typedef __attribute__((ext_vector_type(4))) float f32x4;

__device__ __forceinline__ unsigned short f2bf(float f){
  unsigned int u = __float_as_uint(f);
  u += 0x7fffu + ((u >> 16) & 1u);   // round-to-nearest-even
  return (unsigned short)(u >> 16);
}
__device__ __forceinline__ float bf2f(unsigned short s){
  return __uint_as_float((unsigned int)s << 16);
}

// gather-accumulate: nb batches of 16 neighbors (deg padded to 16), 8 loads
// per batch (2 neighbors per lane-half x 32 col-chunks of 16B)
__device__ __forceinline__ void hop_accum(const unsigned short* __restrict__ src,
                                          int instride, const int* __restrict__ cl,
                                          int nb, int half, float* acc){
  for (int i = 0; i < nb; i++){
    short8 v[8];
    #pragma unroll
    for (int t = 0; t < 8; t++){
      int j = cl[i * 16 + half + 2 * t];
      v[t] = *(const short8*)(src + (size_t)j * instride);
    }
    #pragma unroll
    for (int t = 0; t < 8; t++)
      #pragma unroll
      for (int e = 0; e < 8; e++)
        acc[e] += bf2f((unsigned short)v[t][e]);
  }
}

// ONE persistent cooperative kernel; 5 phases separated by grid.sync().
__global__ __launch_bounds__(256, 2) void coop(
    const float* __restrict__ adj,
    int* __restrict__ deg, int* __restrict__ cols,
    const float* __restrict__ x, const float* __restrict__ W1,
    const float* __restrict__ a1, float* __restrict__ h,
    float* __restrict__ dstv, unsigned short* __restrict__ xb,
    const float* __restrict__ Wsgc, unsigned short* __restrict__ wbT,
    unsigned short* __restrict__ Gb, unsigned short* __restrict__ T1,
    unsigned short* __restrict__ T2, const float* __restrict__ W2,
    float* __restrict__ h2, const float* __restrict__ a2,
    float* __restrict__ maskf, const float* __restrict__ bsgc,
    float* __restrict__ out)
{
  __shared__ union {
    int cnt;                                                            // csr
    struct { unsigned short As[128][72]; unsigned short Bs[64][72]; } g; // gemm 27.6KB
    struct { float v[NNODE + 1]; float red[4]; } sx;                     // softmax 16.4KB
  } sm;
  cg::grid_group gg = cg::this_grid();
  const int bid = blockIdx.x, tid = threadIdx.x;
  const int wave = tid >> 6, lane = tid & 63;

  // ================= P1: csr (tasks 0..4095) | gat_h (..5119) | convert_w (..6143)
  for (int t = bid; t < NNODE + 1024 + 1024; t += GRID){
    if (t < NNODE){
      // CSR row: float4 scan, wave shfl_up scan + 1 LDS atomic per wave;
      // rows padded to mult-of-16 with index NNODE (zeroed row everywhere).
      int row = t;
      if (tid == 0) sm.cnt = 0;
      __syncthreads();
      const float4* arow = (const float4*)(adj + (size_t)row * NNODE);
      int* crow = cols + (size_t)row * CAP;
      #pragma unroll
      for (int k = 0; k < 4; k++){
        int idx = k * 256 + tid;
        float4 v = arow[idx];
        int n0 = (v.x != 0.f), n1 = (v.y != 0.f), n2 = (v.z != 0.f), n3 = (v.w != 0.f);
        int m = n0 + n1 + n2 + n3;
        int pre = m;
        #pragma unroll
        for (int o = 1; o < 64; o <<= 1){
          int tt = __shfl_up(pre, o, 64);
          if (lane >= o) pre += tt;
        }
        int wtot = __shfl(pre, 63, 64);
        int base = 0;
        if (lane == 63 && wtot) base = atomicAdd(&sm.cnt, wtot);
        base = __shfl(base, 63, 64);
        int o2 = base + pre - m;
        int c = idx * 4;
        if (n0){ if (o2 < CAP) crow[o2] = c;     o2++; }
        if (n1){ if (o2 < CAP) crow[o2] = c + 1; o2++; }
        if (n2){ if (o2 < CAP) crow[o2] = c + 2; o2++; }
        if (n3){ if (o2 < CAP) crow[o2] = c + 3; }
      }
      __syncthreads();
      int c = sm.cnt > CAP ? CAP : sm.cnt;
      int c16 = (c + 15) & ~15;
      if (c16 == 0) c16 = 16;
      if (c16 > CAP) c16 = CAP;
      if (tid < c16 - c) crow[c + tid] = NNODE;
      if (tid == 0) deg[row] = c16;
      __syncthreads();                  // cnt reusable next task
    } else if (t < NNODE + 1024){
      // gat_h: h = x@W1, dstv = h.a1[8:16]; lane owns 8 k's; emits xb=bf16(x)
      int gt = t - NNODE;
      if (gt == 0 && tid < HID) h[(size_t)NNODE * HID + tid] = 0.f;   // pad row
      int row = gt * 4 + wave;
      const float* xr8 = x + (size_t)row * INF + lane * 8;
      float4 v0 = ((const float4*)xr8)[0];
      float4 v1 = ((const float4*)xr8)[1];
      float xv[8] = {v0.x, v0.y, v0.z, v0.w, v1.x, v1.y, v1.z, v1.w};
      union { short8 v; unsigned short u[8]; } pk;
      #pragma unroll
      for (int u = 0; u < 8; u++) pk.u[u] = f2bf(xv[u]);
      *(short8*)(xb + (size_t)row * INF + lane * 8) = pk.v;
      float acc[HID];
      #pragma unroll
      for (int f = 0; f < HID; f++) acc[f] = 0.f;
      #pragma unroll
      for (int u = 0; u < 8; u++){
        const float* wp = W1 + (size_t)(lane * 8 + u) * HID;
        #pragma unroll
        for (int f = 0; f < HID; f++) acc[f] += xv[u] * wp[f];
      }
      #pragma unroll
      for (int f = 0; f < HID; f++)
        for (int o = 32; o >= 1; o >>= 1) acc[f] += __shfl_xor(acc[f], o, 64);
      if (lane == 0){
        float d = 0.f;
        #pragma unroll
        for (int f = 0; f < HID; f++){ h[(size_t)row*HID + f] = acc[f]; d += acc[f] * a1[HID + f]; }
        dstv[row] = d;
      }
    } else {
      // convert_w: wbT[c][k] = bf16(W'[k][c]); zero pad rows of Gb/T1/T2
      int idx = (t - NNODE - 1024) * 256 + tid;
      if (idx < 512) Gb[(size_t)NNODE * 512 + idx] = 0;
      if (idx < 256){ T1[(size_t)NNODE * 256 + idx] = 0; T2[(size_t)NNODE * 256 + idx] = 0; }
      int c = idx >> 9, k = idx & 511;
      float val = (c < 256) ? Wsgc[(size_t)k * OUTF + c]
                            : Wsgc[(size_t)(1024 + k) * OUTF + (c - 256)];
      wbT[idx] = f2bf(val);
    }
  }
  __threadfence(); gg.sync();

  // ================= P2: gemm (blocks 0..255, one 128x64 tile each) then
  // softmax-p prologue + agg1 (1024 tasks over all blocks)
  if (bid < 256){
    int bx = bid & 31, by = bid >> 5;
    int row0 = bx * 128, col0 = by * 64;
    int wr = wave >> 1, wc = wave & 1;
    f32x4 acc[4][2];
    #pragma unroll
    for (int i = 0; i < 4; i++)
      #pragma unroll
      for (int j = 0; j < 2; j++)
        #pragma unroll
        for (int e = 0; e < 4; e++) acc[i][j][e] = 0.f;
    int mrow = lane & 15, kq = (lane >> 4) * 8;
    for (int k0 = 0; k0 < 512; k0 += 64){
      #pragma unroll
      for (int ps = 0; ps < 4; ps++){
        int idx = ps * 256 + tid;
        int r = idx >> 3, ko = (idx & 7) * 8;
        *(int4*)(&sm.g.As[r][ko]) = *(const int4*)(xb + ((size_t)(row0 + r) * 512 + k0 + ko));
      }
      #pragma unroll
      for (int ps = 0; ps < 2; ps++){
        int idx = ps * 256 + tid;
        int c = idx >> 3, ko = (idx & 7) * 8;
        *(int4*)(&sm.g.Bs[c][ko]) = *(const int4*)(wbT + ((size_t)(col0 + c) * 512 + k0 + ko));
      }
      __syncthreads();
      #pragma unroll
      for (int kk = 0; kk < 2; kk++){
        short8 a[4], b[2];
        #pragma unroll
        for (int i = 0; i < 4; i++)
          a[i] = *(const short8*)(&sm.g.As[wr * 64 + i * 16 + mrow][kk * 32 + kq]);
        #pragma unroll
        for (int j = 0; j < 2; j++)
          b[j] = *(const short8*)(&sm.g.Bs[wc * 32 + j * 16 + mrow][kk * 32 + kq]);
        #pragma unroll
        for (int i = 0; i < 4; i++)
          #pragma unroll
          for (int j = 0; j < 2; j++)
            acc[i][j] = __builtin_amdgcn_mfma_f32_16x16x32_bf16(a[i], b[j], acc[i][j], 0, 0, 0);
      }
      __syncthreads();
    }
    int crow = (lane >> 4) * 4;   // C/D: col = lane&15, row = (lane>>4)*4 + reg
    int ccol = lane & 15;
    #pragma unroll
    for (int i = 0; i < 4; i++)
      #pragma unroll
      for (int j = 0; j < 2; j++)
        #pragma unroll
        for (int e = 0; e < 4; e++){
          int r = row0 + wr * 64 + i * 16 + crow + e;
          int c = col0 + wc * 32 + j * 16 + ccol;
          Gb[(size_t)r * 512 + c] = f2bf(acc[i][j][e]);
        }
  }
  __syncthreads();
  { // softmax-p prologue (per block, LDS), then this block's agg1 tasks
    if (tid == 0) sm.sx.v[NNODE] = 0.f;
    float mx = -INFINITY;
    for (int i = tid; i < NNODE; i += 256) mx = fmaxf(mx, dstv[i]);
    #pragma unroll
    for (int o = 32; o >= 1; o >>= 1) mx = fmaxf(mx, __shfl_xor(mx, o, 64));
    if (lane == 0) sm.sx.red[wave] = mx;
    __syncthreads();
    mx = fmaxf(fmaxf(sm.sx.red[0], sm.sx.red[1]), fmaxf(sm.sx.red[2], sm.sx.red[3]));
    __syncthreads();
    float sum = 0.f;
    for (int i = tid; i < NNODE; i += 256){ float e = expf(dstv[i] - mx); sm.sx.v[i] = e; sum += e; }
    #pragma unroll
    for (int o = 32; o >= 1; o >>= 1) sum += __shfl_xor(sum, o, 64);
    if (lane == 0) sm.sx.red[wave] = sum;
    __syncthreads();
    float inv = 1.0f / (sm.sx.red[0] + sm.sx.red[1] + sm.sx.red[2] + sm.sx.red[3]);
    for (int i = tid; i < NNODE; i += 256) sm.sx.v[i] *= inv;
    __syncthreads();
    for (int t = bid; t < 1280; t += GRID){
      if (t < 256) continue;
      int row = (t - 256) * 4 + wave;
      const int* cl = cols + (size_t)row * CAP;
      int d = deg[row];
      int ng = lane >> 3, f = lane & 7;
      float acc = 0.f;
      for (int n = ng; n < d; n += 8){
        int j = cl[n];          // pad j=NNODE: p=0, h row zeroed -> adds 0
        acc += sm.sx.v[j] * h[(size_t)j * HID + f];
      }
      acc += __shfl_xor(acc, 8, 64);
      acc += __shfl_xor(acc, 16, 64);
      acc += __shfl_xor(acc, 32, 64);
      float e = acc > 0.f ? acc : expm1f(acc);
      float tt = e * W2[f];
      tt += __shfl_xor(tt, 1, 64);
      tt += __shfl_xor(tt, 2, 64);
      tt += __shfl_xor(tt, 4, 64);
      if (lane == 0) h2[row] = tt;
    }
  }
  __threadfence(); gg.sync();

  // ================= P3: hop1 (T1 = A @ Gb[:,256:512]) then softmax-q + scores
  for (int t = bid; t < 1024; t += GRID){
    int row = t * 4 + wave;
    const int* cl = cols + (size_t)row * CAP;
    int nb = deg[row] >> 4;
    int half = lane >> 5, cid = lane & 31;
    const unsigned short* src = Gb + 256 + cid * 8;
    float acc[8];
    #pragma unroll
    for (int e = 0; e < 8; e++) acc[e] = 0.f;
    hop_accum(src, 512, cl, nb, half, acc);
    #pragma unroll
    for (int e = 0; e < 8; e++) acc[e] += __shfl_xor(acc[e], 32, 64);
    if (half == 0){
      union { short8 v; unsigned short u[8]; } pk;
      #pragma unroll
      for (int e = 0; e < 8; e++) pk.u[e] = f2bf(acc[e]);
      *(short8*)(T1 + (size_t)row * OUTF + cid * 8) = pk.v;
    }
  }
  __syncthreads();
  { // softmax-q prologue (q[j] = softmax(a2[1]*h2)[j]*h2[j]) + scores/mask
    float s2 = a2[1];
    if (tid == 0) sm.sx.v[NNODE] = 0.f;
    float mx = -INFINITY;
    for (int i = tid; i < NNODE; i += 256) mx = fmaxf(mx, s2 * h2[i]);
    #pragma unroll
    for (int o = 32; o >= 1; o >>= 1) mx = fmaxf(mx, __shfl_xor(mx, o, 64));
    if (lane == 0) sm.sx.red[wave] = mx;
    __syncthreads();
    mx = fmaxf(fmaxf(sm.sx.red[0], sm.sx.red[1]), fmaxf(sm.sx.red[2], sm.sx.red[3]));
    __syncthreads();
    float sum = 0.f;
    for (int i = tid; i < NNODE; i += 256){ float e = expf(s2 * h2[i] - mx); sm.sx.v[i] = e; sum += e; }
    #pragma unroll
    for (int o = 32; o >= 1; o >>= 1) sum += __shfl_xor(sum, o, 64);
    if (lane == 0) sm.sx.red[wave] = sum;
    __syncthreads();
    float inv = 1.0f / (sm.sx.red[0] + sm.sx.red[1] + sm.sx.red[2] + sm.sx.red[3]);
    for (int i = tid; i < NNODE; i += 256) sm.sx.v[i] = sm.sx.v[i] * inv * h2[i];
    __syncthreads();
    for (int t = bid; t < 1024; t += GRID){
      int row = t * 4 + wave;
      const int* cl = cols + (size_t)row * CAP;
      int d = deg[row];
      float s = 0.f;
      for (int n = lane; n < d; n += 64) s += sm.sx.v[cl[n]];   // pad -> 0
      #pragma unroll
      for (int o = 32; o >= 1; o >>= 1) s += __shfl_xor(s, o, 64);
      if (lane == 0){
        float e = s > 0.f ? s : expm1f(s);
        maskf[row] = (e > 0.7f) ? 1.0f : 0.0f;
      }
    }
  }
  __threadfence(); gg.sync();

  // ================= P4: T2 = A @ T1  (full: T2[j] consumed for all neighbors
  // of mask-0 rows — no early-out legal)
  for (int t = bid; t < 1024; t += GRID){
    int row = t * 4 + wave;
    const int* cl = cols + (size_t)row * CAP;
    int nb = deg[row] >> 4;
    int half = lane >> 5, cid = lane & 31;
    const unsigned short* src = T1 + cid * 8;
    float acc[8];
    #pragma unroll
    for (int e = 0; e < 8; e++) acc[e] = 0.f;
    hop_accum(src, 256, cl, nb, half, acc);
    #pragma unroll
    for (int e = 0; e < 8; e++) acc[e] += __shfl_xor(acc[e], 32, 64);
    if (half == 0){
      union { short8 v; unsigned short u[8]; } pk;
      #pragma unroll
      for (int e = 0; e < 8; e++) pk.u[e] = f2bf(acc[e]);
      *(short8*)(T2 + (size_t)row * OUTF + cid * 8) = pk.v;
    }
  }
  __threadfence(); gg.sync();

  // ================= P5: final hop, per-row source select (mask=1: Gb[:, :256],
  // mask=0: T2) + bias, fp32 output
  for (int t = bid; t < 1024; t += GRID){
    int row = t * 4 + wave;
    const int* cl = cols + (size_t)row * CAP;
    int nb = deg[row] >> 4;
    bool m = maskf[row] != 0.0f;          // wave-uniform
    const unsigned short* base = m ? Gb : T2;
    int instride = m ? 512 : 256;
    int half = lane >> 5, cid = lane & 31;
    const unsigned short* src = base + cid * 8;
    float acc[8];
    #pragma unroll
    for (int e = 0; e < 8; e++) acc[e] = 0.f;
    hop_accum(src, instride, cl, nb, half, acc);
    #pragma unroll
    for (int e = 0; e < 8; e++) acc[e] += __shfl_xor(acc[e], 32, 64);
    if (half == 0){
      f32x4 b0 = ((const f32x4*)(bsgc + cid * 8))[0];
      f32x4 b1 = ((const f32x4*)(bsgc + cid * 8 + 4))[0];
      f32x4 o0, o1;
      #pragma unroll
      for (int e = 0; e < 4; e++){ o0[e] = acc[e] + b0[e]; o1[e] = acc[4 + e] + b1[e]; }
      float* orow = out + (size_t)row * OUTF + cid * 8;
      ((f32x4*)orow)[0] = o0;
      ((f32x4*)(orow + 4))[0] = o1;
    }
  }
}

extern "C" void kernel_launch(void* const* d_in, const int* in_sizes, int n_in,
                              void* d_out, int out_size, void* d_ws, size_t ws_size,
                              hipStream_t stream) {
  const float* x    = (const float*)d_in[0];
  const float* adj  = (const float*)d_in[1];
  const float* W1   = (const float*)d_in[2];
  const float* a1   = (const float*)d_in[3];
  const float* W2   = (const float*)d_in[4];
  const float* a2   = (const float*)d_in[5];
  const float* Wsgc = (const float*)d_in[6];
  const float* bsgc = (const float*)d_in[7];
  float* out = (float*)d_out;

  char* w = (char*)d_ws;
  size_t off = 0;
  auto carve = [&](size_t bytes) -> char* {
    char* p = w + off;
    off += (bytes + 255) & ~(size_t)255;
    return p;
  };
  int*   deg   = (int*)carve((size_t)NNODE * 4);
  int*   cols  = (int*)carve((size_t)NNODE * CAP * 4);
  float* h     = (float*)carve((size_t)(NNODE + 1) * HID * 4);
  float* dstv  = (float*)carve((size_t)NNODE * 4);
  float* h2    = (float*)carve((size_t)NNODE * 4);
  float* maskf = (float*)carve((size_t)NNODE * 4);
  unsigned short* wbT = (unsigned short*)carve((size_t)512 * 512 * 2);
  unsigned short* xb  = (unsigned short*)carve((size_t)NNODE * INF * 2);
  unsigned short* Gb  = (unsigned short*)carve((size_t)(NNODE + 1) * 512 * 2);
  unsigned short* T1  = (unsigned short*)carve((size_t)(NNODE + 1) * OUTF * 2);
  unsigned short* T2  = (unsigned short*)carve((size_t)(NNODE + 1) * OUTF * 2);

  void* args[] = {
    (void*)&adj, (void*)&deg, (void*)&cols, (void*)&x, (void*)&W1, (void*)&a1,
    (void*)&h, (void*)&dstv, (void*)&xb, (void*)&Wsgc, (void*)&wbT,
    (void*)&Gb, (void*)&T1, (void*)&T2, (void*)&W2, (void*)&h2,
    (void*)&a2, (void*)&maskf, (void*)&bsgc, (void*)&out };
  hipLaunchCooperativeKernel((const void*)coop, dim3(GRID), dim3(256), args, 0, stream);
}

// Round 9
// 166.201 us; speedup vs baseline: 3.7358x; 3.7358x over previous
//
#include <hip/hip_runtime.h>
#include <hip/hip_bf16.h>
#include <cstddef>

#define NNODE 4096
#define INF   512
#define OUTF  256
#define HID   8
#define CAP   128   // max degree; Binomial(4096,0.01) max ~67; padded to mult-of-8, <=72

typedef __attribute__((ext_vector_type(8))) short short8;
typedef __attribute__((ext_vector_type(4))) float f32x4;

__device__ __forceinline__ unsigned short f2bf(float f){
  unsigned int u = __float_as_uint(f);
  u += 0x7fffu + ((u >> 16) & 1u);   // round-to-nearest-even
  return (unsigned short)(u >> 16);
}
__device__ __forceinline__ float bf2f(unsigned short s){
  return __uint_as_float((unsigned int)s << 16);
}

// ================================================================ dispatch 0
// PREP: gat_h (blocks 0..1023) + convert_w (1024..2047).  Small (~2us); runs
// first so D1's gemm has xb/wbT ready while csr's 67MB adj scan fills D1.
__global__ __launch_bounds__(256) void prep(const float* __restrict__ x,
                                            const float* __restrict__ W1,
                                            const float* __restrict__ a1,
                                            float* __restrict__ h,
                                            float* __restrict__ dstv,
                                            unsigned short* __restrict__ xb,
                                            const float* __restrict__ Wsgc,
                                            unsigned short* __restrict__ wbT,
                                            unsigned short* __restrict__ Gb,
                                            unsigned short* __restrict__ T1,
                                            unsigned short* __restrict__ T2){
  int bid = blockIdx.x, tid = threadIdx.x;
  if (bid < 1024){
    // ---- gat_h: h = x @ W1, dstv = h . a1[8:16]; one wave per row.
    // FUSED: emits xb = bf16(x) for the MFMA GEMM.
    if (bid == 0 && tid < HID) h[(size_t)NNODE * HID + tid] = 0.f;  // pad row
    int wave = tid >> 6, lane = tid & 63;
    int row = bid * 4 + wave;
    const float* xr = x + (size_t)row * INF;
    unsigned short* xbr = xb + (size_t)row * INF;
    float acc[HID];
    #pragma unroll
    for (int f = 0; f < HID; f++) acc[f] = 0.f;
    for (int k = lane; k < INF; k += 64){
      float xv = xr[k];
      xbr[k] = f2bf(xv);
      const float* wp = W1 + (size_t)k * HID;
      #pragma unroll
      for (int f = 0; f < HID; f++) acc[f] += xv * wp[f];
    }
    #pragma unroll
    for (int f = 0; f < HID; f++)
      for (int o = 32; o >= 1; o >>= 1) acc[f] += __shfl_xor(acc[f], o, 64);
    if (lane == 0){
      float d = 0.f;
      #pragma unroll
      for (int f = 0; f < HID; f++){ h[(size_t)row*HID + f] = acc[f]; d += acc[f] * a1[HID + f]; }
      dstv[row] = d;
    }
  } else {
    // ---- convert_w: wbT[c][k] = bf16(W'[k][c]); + zero pad rows of Gb/T1/T2
    int idx = (bid - 1024) * 256 + tid;   // 0 .. 262143
    if (idx < 512) Gb[(size_t)NNODE * 512 + idx] = 0;
    if (idx < 256){ T1[(size_t)NNODE * 256 + idx] = 0; T2[(size_t)NNODE * 256 + idx] = 0; }
    int c = idx >> 9, k = idx & 511;
    float val = (c < 256) ? Wsgc[(size_t)k * OUTF + c]
                          : Wsgc[(size_t)(1024 + k) * OUTF + (c - 256)];
    wbT[idx] = f2bf(val);
  }
}

// ================================================================ dispatch 1
// CSR_GEMM: gemm (blocks 0..255, 128x64 tiles, issued first) + csr scan
// (blocks 256..4351).  Independent: gemm xb,wbT->Gb; csr adj->deg,cols.
// The ~8us GEMM hides entirely under the 67MB/~13us adj stream.
__global__ __launch_bounds__(256) void csr_gemm(const float* __restrict__ adj,
                                                int* __restrict__ deg,
                                                int* __restrict__ cols,
                                                const unsigned short* __restrict__ XB,
                                                const unsigned short* __restrict__ BT,
                                                unsigned short* __restrict__ Gb){
  __shared__ union {
    int cnt;                                                             // csr
    struct { unsigned short As[128][72]; unsigned short Bs[64][72]; } g; // 27.6 KB
  } sm;
  int bid = blockIdx.x, tid = threadIdx.x;
  int wave = tid >> 6, lane = tid & 63;

  if (bid < 256){
    // ---- bf16 MFMA GEMM: Gb[4096][512](bf16) = xb @ W'.  128x64 tile,
    // 4 waves 2x2, wave = 4x2 of 16x16x32 MFMAs, BK=64, bf16 epilogue.
    // (body verified in R7 coop P2)
    int bx = bid & 31, by = bid >> 5;
    int row0 = bx * 128, col0 = by * 64;
    int wr = wave >> 1, wc = wave & 1;
    f32x4 acc[4][2];
    #pragma unroll
    for (int i = 0; i < 4; i++)
      #pragma unroll
      for (int j = 0; j < 2; j++)
        #pragma unroll
        for (int e = 0; e < 4; e++) acc[i][j][e] = 0.f;
    int mrow = lane & 15, kq = (lane >> 4) * 8;
    for (int k0 = 0; k0 < 512; k0 += 64){
      #pragma unroll
      for (int ps = 0; ps < 4; ps++){
        int idx = ps * 256 + tid;
        int r = idx >> 3, ko = (idx & 7) * 8;
        *(int4*)(&sm.g.As[r][ko]) = *(const int4*)(XB + ((size_t)(row0 + r) * 512 + k0 + ko));
      }
      #pragma unroll
      for (int ps = 0; ps < 2; ps++){
        int idx = ps * 256 + tid;
        int c = idx >> 3, ko = (idx & 7) * 8;
        *(int4*)(&sm.g.Bs[c][ko]) = *(const int4*)(BT + ((size_t)(col0 + c) * 512 + k0 + ko));
      }
      __syncthreads();
      #pragma unroll
      for (int kk = 0; kk < 2; kk++){
        short8 a[4], b[2];
        #pragma unroll
        for (int i = 0; i < 4; i++)
          a[i] = *(const short8*)(&sm.g.As[wr * 64 + i * 16 + mrow][kk * 32 + kq]);
        #pragma unroll
        for (int j = 0; j < 2; j++)
          b[j] = *(const short8*)(&sm.g.Bs[wc * 32 + j * 16 + mrow][kk * 32 + kq]);
        #pragma unroll
        for (int i = 0; i < 4; i++)
          #pragma unroll
          for (int j = 0; j < 2; j++)
            acc[i][j] = __builtin_amdgcn_mfma_f32_16x16x32_bf16(a[i], b[j], acc[i][j], 0, 0, 0);
      }
      __syncthreads();
    }
    int crow = (lane >> 4) * 4;   // C/D: col = lane&15, row = (lane>>4)*4 + reg
    int ccol = lane & 15;
    #pragma unroll
    for (int i = 0; i < 4; i++)
      #pragma unroll
      for (int j = 0; j < 2; j++)
        #pragma unroll
        for (int e = 0; e < 4; e++){
          int r = row0 + wr * 64 + i * 16 + crow + e;
          int c = col0 + wc * 32 + j * 16 + ccol;
          Gb[(size_t)r * 512 + c] = f2bf(acc[i][j][e]);
        }

  } else {
    // ---- CSR build: one block per row; float4 scan, per-thread LDS atomic
    // compaction (order irrelevant — consumers are sums).  Rows PADDED to a
    // multiple of 8 with index NNODE (zeroed row in every gather source).
    int row = bid - 256;
    if (tid == 0) sm.cnt = 0;
    __syncthreads();
    const float4* arow = (const float4*)(adj + (size_t)row * NNODE);
    int* crow = cols + (size_t)row * CAP;
    #pragma unroll
    for (int k = 0; k < 4; k++){
      int idx = k * 256 + tid;          // float4 index
      float4 v = arow[idx];
      int n0 = (v.x != 0.f), n1 = (v.y != 0.f), n2 = (v.z != 0.f), n3 = (v.w != 0.f);
      int m = n0 + n1 + n2 + n3;
      if (m){
        int base = atomicAdd(&sm.cnt, m);
        int c = idx * 4;
        if (n0){ if (base < CAP) crow[base] = c;     base++; }
        if (n1){ if (base < CAP) crow[base] = c + 1; base++; }
        if (n2){ if (base < CAP) crow[base] = c + 2; base++; }
        if (n3){ if (base < CAP) crow[base] = c + 3; }
      }
    }
    __syncthreads();
    int c = sm.cnt > CAP ? CAP : sm.cnt;
    int c8 = (c + 7) & ~7;
    if (c8 > CAP) c8 = CAP;
    if (tid < c8 - c) crow[c + tid] = NNODE;   // pad with zero-row index
    if (tid == 0) deg[row] = c8;
  }
}

// ================================================================ dispatch 2
// HOP1_AGG: hop1 T1 = adj @ Gb[:,256:512] (blocks 0..1023, heavy, first) +
// gat_agg1 with inline softmax-p prologue (blocks 1024..2047).
__global__ __launch_bounds__(256) void hop1_agg(const unsigned short* __restrict__ Gb,
                                                unsigned short* __restrict__ T1,
                                                const float* __restrict__ h,
                                                const float* __restrict__ dstv,
                                                const int* __restrict__ deg,
                                                const int* __restrict__ cols,
                                                const float* __restrict__ W2,
                                                float* __restrict__ h2){
  __shared__ float p[NNODE + 1];
  __shared__ float red[4];
  int bid = blockIdx.x, tid = threadIdx.x;
  int wave = tid >> 6, lane = tid & 63;

  if (bid < 1024){
    // ---- hop1: wave = 2 neighbors x 32 col-chunks of Gb[:, 256:512]
    int row = bid * 4 + wave;
    const int* cl = cols + (size_t)row * CAP;
    int d = deg[row];
    int half = lane >> 5, cid = lane & 31;
    const unsigned short* src = Gb + 256 + cid * 8;
    float acc[8];
    #pragma unroll
    for (int e = 0; e < 8; e++) acc[e] = 0.f;
    int n = 0;
    for (; n + 16 <= d; n += 16){
      int j0 = cl[n +      half], j1 = cl[n + 2  + half], j2 = cl[n + 4  + half], j3 = cl[n + 6  + half];
      int j4 = cl[n + 8  + half], j5 = cl[n + 10 + half], j6 = cl[n + 12 + half], j7 = cl[n + 14 + half];
      short8 v0 = *(const short8*)(src + (size_t)j0 * 512);
      short8 v1 = *(const short8*)(src + (size_t)j1 * 512);
      short8 v2 = *(const short8*)(src + (size_t)j2 * 512);
      short8 v3 = *(const short8*)(src + (size_t)j3 * 512);
      short8 v4 = *(const short8*)(src + (size_t)j4 * 512);
      short8 v5 = *(const short8*)(src + (size_t)j5 * 512);
      short8 v6 = *(const short8*)(src + (size_t)j6 * 512);
      short8 v7 = *(const short8*)(src + (size_t)j7 * 512);
      #pragma unroll
      for (int e = 0; e < 8; e++){
        acc[e] += bf2f((unsigned short)v0[e]) + bf2f((unsigned short)v1[e])
                + bf2f((unsigned short)v2[e]) + bf2f((unsigned short)v3[e])
                + bf2f((unsigned short)v4[e]) + bf2f((unsigned short)v5[e])
                + bf2f((unsigned short)v6[e]) + bf2f((unsigned short)v7[e]);
      }
    }
    if (n < d){   // exactly 8 remain (deg is mult of 8)
      int j0 = cl[n + half], j1 = cl[n + 2 + half], j2 = cl[n + 4 + half], j3 = cl[n + 6 + half];
      short8 v0 = *(const short8*)(src + (size_t)j0 * 512);
      short8 v1 = *(const short8*)(src + (size_t)j1 * 512);
      short8 v2 = *(const short8*)(src + (size_t)j2 * 512);
      short8 v3 = *(const short8*)(src + (size_t)j3 * 512);
      #pragma unroll
      for (int e = 0; e < 8; e++){
        acc[e] += bf2f((unsigned short)v0[e]) + bf2f((unsigned short)v1[e])
                + bf2f((unsigned short)v2[e]) + bf2f((unsigned short)v3[e]);
      }
    }
    #pragma unroll
    for (int e = 0; e < 8; e++) acc[e] += __shfl_xor(acc[e], 32, 64);
    if (half == 0){
      union { short8 v; unsigned short u[8]; } pk;
      #pragma unroll
      for (int e = 0; e < 8; e++) pk.u[e] = f2bf(acc[e]);
      *(short8*)(T1 + (size_t)row * OUTF + cid * 8) = pk.v;
    }

  } else {
    // ---- gat_agg1 with inline softmax-p prologue (p in LDS, per block).
    if (tid == 0) p[NNODE] = 0.f;                 // zero pad entry
    float mx = -INFINITY;
    for (int i = tid; i < NNODE; i += 256) mx = fmaxf(mx, dstv[i]);
    #pragma unroll
    for (int o = 32; o >= 1; o >>= 1) mx = fmaxf(mx, __shfl_xor(mx, o, 64));
    if (lane == 0) red[wave] = mx;
    __syncthreads();
    mx = fmaxf(fmaxf(red[0], red[1]), fmaxf(red[2], red[3]));
    __syncthreads();
    float sum = 0.f;
    for (int i = tid; i < NNODE; i += 256){ float e = expf(dstv[i] - mx); p[i] = e; sum += e; }
    #pragma unroll
    for (int o = 32; o >= 1; o >>= 1) sum += __shfl_xor(sum, o, 64);
    if (lane == 0) red[wave] = sum;
    __syncthreads();
    float inv = 1.0f / (red[0] + red[1] + red[2] + red[3]);
    for (int i = tid; i < NNODE; i += 256) p[i] *= inv;
    __syncthreads();

    int row = (bid - 1024) * 4 + wave;
    const int* cl = cols + (size_t)row * CAP;
    int d = deg[row];
    int ng = lane >> 3;      // neighbor group 0..7
    int f  = lane & 7;       // feature 0..7
    float acc = 0.f;
    for (int n = ng; n < d; n += 8){
      int j = cl[n];         // pad j=NNODE: p=0, h row zeroed -> adds 0
      acc += p[j] * h[(size_t)j * HID + f];
    }
    acc += __shfl_xor(acc, 8, 64);
    acc += __shfl_xor(acc, 16, 64);
    acc += __shfl_xor(acc, 32, 64);
    float e = acc > 0.f ? acc : expm1f(acc);
    float t = e * W2[f];
    t += __shfl_xor(t, 1, 64);
    t += __shfl_xor(t, 2, 64);
    t += __shfl_xor(t, 4, 64);
    if (lane == 0) h2[row] = t;
  }
}

// ================================================================ dispatch 3
// HOP2_SCORES: hop2 T2 = adj @ T1 (blocks 0..1023 — full; T2[j] is consumed
// for all neighbors of mask-0 rows, no early-out) + scores/mask with inline
// softmax-q prologue (blocks 1024..2047).
__global__ __launch_bounds__(256) void hop2_scores(const unsigned short* __restrict__ T1,
                                                   unsigned short* __restrict__ T2,
                                                   const float* __restrict__ h2,
                                                   const float* __restrict__ a2,
                                                   const int* __restrict__ deg,
                                                   const int* __restrict__ cols,
                                                   float* __restrict__ maskf){
  __shared__ float q[NNODE + 1];
  __shared__ float red[4];
  int bid = blockIdx.x, tid = threadIdx.x;
  int wave = tid >> 6, lane = tid & 63;

  if (bid < 1024){
    // ---- hop2
    int row = bid * 4 + wave;
    const int* cl = cols + (size_t)row * CAP;
    int d = deg[row];
    int half = lane >> 5, cid = lane & 31;
    const unsigned short* src = T1 + cid * 8;
    float acc[8];
    #pragma unroll
    for (int e = 0; e < 8; e++) acc[e] = 0.f;
    int n = 0;
    for (; n + 16 <= d; n += 16){
      int j0 = cl[n +      half], j1 = cl[n + 2  + half], j2 = cl[n + 4  + half], j3 = cl[n + 6  + half];
      int j4 = cl[n + 8  + half], j5 = cl[n + 10 + half], j6 = cl[n + 12 + half], j7 = cl[n + 14 + half];
      short8 v0 = *(const short8*)(src + (size_t)j0 * 256);
      short8 v1 = *(const short8*)(src + (size_t)j1 * 256);
      short8 v2 = *(const short8*)(src + (size_t)j2 * 256);
      short8 v3 = *(const short8*)(src + (size_t)j3 * 256);
      short8 v4 = *(const short8*)(src + (size_t)j4 * 256);
      short8 v5 = *(const short8*)(src + (size_t)j5 * 256);
      short8 v6 = *(const short8*)(src + (size_t)j6 * 256);
      short8 v7 = *(const short8*)(src + (size_t)j7 * 256);
      #pragma unroll
      for (int e = 0; e < 8; e++){
        acc[e] += bf2f((unsigned short)v0[e]) + bf2f((unsigned short)v1[e])
                + bf2f((unsigned short)v2[e]) + bf2f((unsigned short)v3[e])
                + bf2f((unsigned short)v4[e]) + bf2f((unsigned short)v5[e])
                + bf2f((unsigned short)v6[e]) + bf2f((unsigned short)v7[e]);
      }
    }
    if (n < d){   // exactly 8 remain
      int j0 = cl[n + half], j1 = cl[n + 2 + half], j2 = cl[n + 4 + half], j3 = cl[n + 6 + half];
      short8 v0 = *(const short8*)(src + (size_t)j0 * 256);
      short8 v1 = *(const short8*)(src + (size_t)j1 * 256);
      short8 v2 = *(const short8*)(src + (size_t)j2 * 256);
      short8 v3 = *(const short8*)(src + (size_t)j3 * 256);
      #pragma unroll
      for (int e = 0; e < 8; e++){
        acc[e] += bf2f((unsigned short)v0[e]) + bf2f((unsigned short)v1[e])
                + bf2f((unsigned short)v2[e]) + bf2f((unsigned short)v3[e]);
      }
    }
    #pragma unroll
    for (int e = 0; e < 8; e++) acc[e] += __shfl_xor(acc[e], 32, 64);
    if (half == 0){
      union { short8 v; unsigned short u[8]; } pk;
      #pragma unroll
      for (int e = 0; e < 8; e++) pk.u[e] = f2bf(acc[e]);
      *(short8*)(T2 + (size_t)row * OUTF + cid * 8) = pk.v;
    }

  } else {
    // ---- scores/mask with inline softmax-q prologue (q in LDS).
    float s2 = a2[1];
    if (tid == 0) q[NNODE] = 0.f;                 // zero pad entry
    float mx = -INFINITY;
    for (int i = tid; i < NNODE; i += 256) mx = fmaxf(mx, s2 * h2[i]);
    #pragma unroll
    for (int o = 32; o >= 1; o >>= 1) mx = fmaxf(mx, __shfl_xor(mx, o, 64));
    if (lane == 0) red[wave] = mx;
    __syncthreads();
    mx = fmaxf(fmaxf(red[0], red[1]), fmaxf(red[2], red[3]));
    __syncthreads();
    float sum = 0.f;
    for (int i = tid; i < NNODE; i += 256){ float e = expf(s2 * h2[i] - mx); q[i] = e; sum += e; }
    #pragma unroll
    for (int o = 32; o >= 1; o >>= 1) sum += __shfl_xor(sum, o, 64);
    if (lane == 0) red[wave] = sum;
    __syncthreads();
    float inv = 1.0f / (red[0] + red[1] + red[2] + red[3]);
    for (int i = tid; i < NNODE; i += 256) q[i] = q[i] * inv * h2[i];
    __syncthreads();

    int row = (bid - 1024) * 4 + wave;
    const int* cl = cols + (size_t)row * CAP;
    int d = deg[row];
    float s = 0.f;
    for (int n = lane; n < d; n += 64) s += q[cl[n]];   // pad -> q[NNODE]=0
    #pragma unroll
    for (int o = 32; o >= 1; o >>= 1) s += __shfl_xor(s, o, 64);
    if (lane == 0){
      float e = s > 0.f ? s : expm1f(s);
      maskf[row] = (e > 0.7f) ? 1.0f : 0.0f;
    }
  }
}

// ================================================================ dispatch 4
// final hop + epilogue with per-row pruning: mask=1 rows gather Gb[:, :256],
// mask=0 rows gather T2.  fp32 output + bias.
__global__ __launch_bounds__(256) void hop_final_bf(const unsigned short* __restrict__ Gb,
                                                    const unsigned short* __restrict__ T2,
                                                    const float* __restrict__ maskf,
                                                    const float* __restrict__ b,
                                                    float* __restrict__ out,
                                                    const int* __restrict__ deg,
                                                    const int* __restrict__ cols){
  int wave = threadIdx.x >> 6, lane = threadIdx.x & 63;
  int row = blockIdx.x * 4 + wave;
  const int* cl = cols + (size_t)row * CAP;
  int d = deg[row];
  bool m = maskf[row] != 0.0f;             // wave-uniform
  const unsigned short* base = m ? Gb : T2;
  int instride = m ? 512 : 256;
  int half = lane >> 5, cid = lane & 31;
  const unsigned short* src = base + cid * 8;
  float acc[8];
  #pragma unroll
  for (int e = 0; e < 8; e++) acc[e] = 0.f;
  int n = 0;
  for (; n + 16 <= d; n += 16){
    int j0 = cl[n +      half], j1 = cl[n + 2  + half], j2 = cl[n + 4  + half], j3 = cl[n + 6  + half];
    int j4 = cl[n + 8  + half], j5 = cl[n + 10 + half], j6 = cl[n + 12 + half], j7 = cl[n + 14 + half];
    short8 v0 = *(const short8*)(src + (size_t)j0 * instride);
    short8 v1 = *(const short8*)(src + (size_t)j1 * instride);
    short8 v2 = *(const short8*)(src + (size_t)j2 * instride);
    short8 v3 = *(const short8*)(src + (size_t)j3 * instride);
    short8 v4 = *(const short8*)(src + (size_t)j4 * instride);
    short8 v5 = *(const short8*)(src + (size_t)j5 * instride);
    short8 v6 = *(const short8*)(src + (size_t)j6 * instride);
    short8 v7 = *(const short8*)(src + (size_t)j7 * instride);
    #pragma unroll
    for (int e = 0; e < 8; e++){
      acc[e] += bf2f((unsigned short)v0[e]) + bf2f((unsigned short)v1[e])
              + bf2f((unsigned short)v2[e]) + bf2f((unsigned short)v3[e])
              + bf2f((unsigned short)v4[e]) + bf2f((unsigned short)v5[e])
              + bf2f((unsigned short)v6[e]) + bf2f((unsigned short)v7[e]);
    }
  }
  if (n < d){   // exactly 8 remain
    int j0 = cl[n + half], j1 = cl[n + 2 + half], j2 = cl[n + 4 + half], j3 = cl[n + 6 + half];
    short8 v0 = *(const short8*)(src + (size_t)j0 * instride);
    short8 v1 = *(const short8*)(src + (size_t)j1 * instride);
    short8 v2 = *(const short8*)(src + (size_t)j2 * instride);
    short8 v3 = *(const short8*)(src + (size_t)j3 * instride);
    #pragma unroll
    for (int e = 0; e < 8; e++){
      acc[e] += bf2f((unsigned short)v0[e]) + bf2f((unsigned short)v1[e])
              + bf2f((unsigned short)v2[e]) + bf2f((unsigned short)v3[e]);
    }
  }
  #pragma unroll
  for (int e = 0; e < 8; e++) acc[e] += __shfl_xor(acc[e], 32, 64);
  if (half == 0){
    f32x4 b0 = ((const f32x4*)(b + cid * 8))[0];
    f32x4 b1 = ((const f32x4*)(b + cid * 8 + 4))[0];
    f32x4 o0, o1;
    #pragma unroll
    for (int e = 0; e < 4; e++){ o0[e] = acc[e] + b0[e]; o1[e] = acc[4 + e] + b1[e]; }
    float* orow = out + (size_t)row * OUTF + cid * 8;
    ((f32x4*)orow)[0] = o0;
    ((f32x4*)(orow + 4))[0] = o1;
  }
}

extern "C" void kernel_launch(void* const* d_in, const int* in_sizes, int n_in,
                              void* d_out, int out_size, void* d_ws, size_t ws_size,
                              hipStream_t stream) {
  const float* x    = (const float*)d_in[0];
  const float* adj  = (const float*)d_in[1];
  const float* W1   = (const float*)d_in[2];
  const float* a1   = (const float*)d_in[3];
  const float* W2   = (const float*)d_in[4];
  const float* a2   = (const float*)d_in[5];
  const float* Wsgc = (const float*)d_in[6];
  const float* bsgc = (const float*)d_in[7];
  float* out = (float*)d_out;

  char* w = (char*)d_ws;
  size_t off = 0;
  auto carve = [&](size_t bytes) -> char* {
    char* p = w + off;
    off += (bytes + 255) & ~(size_t)255;
    return p;
  };
  int*   deg   = (int*)carve((size_t)NNODE * 4);
  int*   cols  = (int*)carve((size_t)NNODE * CAP * 4);
  float* h     = (float*)carve((size_t)(NNODE + 1) * HID * 4);
  float* dstv  = (float*)carve((size_t)NNODE * 4);
  float* h2    = (float*)carve((size_t)NNODE * 4);
  float* maskf = (float*)carve((size_t)NNODE * 4);
  unsigned short* wbT = (unsigned short*)carve((size_t)512 * 512 * 2);
  unsigned short* xb  = (unsigned short*)carve((size_t)NNODE * INF * 2);
  unsigned short* Gb  = (unsigned short*)carve((size_t)(NNODE + 1) * 512 * 2);
  unsigned short* T1  = (unsigned short*)carve((size_t)(NNODE + 1) * OUTF * 2);
  unsigned short* T2  = (unsigned short*)carve((size_t)(NNODE + 1) * OUTF * 2);

  // D0: gat_h(+xb) + convert_w  (small; produces gemm inputs)
  prep<<<2048, 256, 0, stream>>>(x, W1, a1, h, dstv, xb, Wsgc, wbT, Gb, T1, T2);
  // D1: gemm (first 256 blocks) + csr adj scan (next 4096) — gemm hides
  //     under the 67MB adj stream
  csr_gemm<<<256 + 4096, 256, 0, stream>>>(adj, deg, cols, xb, wbT, Gb);
  // D2: hop1 (first 1024) + agg1-with-softmax-p (next 1024)
  hop1_agg<<<2048, 256, 0, stream>>>(Gb, T1, h, dstv, deg, cols, W2, h2);
  // D3: hop2 (first 1024) + scores-with-softmax-q (next 1024)
  hop2_scores<<<2048, 256, 0, stream>>>(T1, T2, h2, a2, deg, cols, maskf);
  // D4: final hop, per-row pruned source select + bias
  hop_final_bf<<<NNODE / 4, 256, 0, stream>>>(Gb, T2, maskf, bsgc, out, deg, cols);
}